// Round 7
// baseline (536.463 us; speedup 1.0000x reference)
//
#include <hip/hip_runtime.h>
#include <hip/hip_bf16.h>

#define NTOK 8192
#define SCC  16
#define CD   128
#define WD   512
#define OD   1024
#define ED   640   // WD + CD
#define TW   4     // tokens per scan workgroup

typedef __attribute__((ext_vector_type(8))) short short8;
typedef __attribute__((ext_vector_type(4))) float f32x4;

__device__ __forceinline__ unsigned short f2bf(float f) {
    union { float f; unsigned u; } v; v.f = f;
    unsigned r = v.u + 0x7FFF + ((v.u >> 16) & 1);   // RNE
    return (unsigned short)(r >> 16);
}

// ---------------------------------------------------------------------------
// Deterministic stable counting sort of tokens by length (16 bins).
// ws ints: [0..15]=hist [16..31]=base [32..47]=unused [48..48+NTOK)=order
// ---------------------------------------------------------------------------
__global__ void sort_zero(int* s) { if (threadIdx.x < 48) s[threadIdx.x] = 0; }

__global__ void sort_hist(const int* __restrict__ lengths, int* __restrict__ s) {
    const int i = blockIdx.x * 256 + threadIdx.x;
    if (i < NTOK) atomicAdd(&s[lengths[i] - 1], 1);
}

__global__ void sort_prefix(int* s) {
    if (threadIdx.x == 0) {
        int acc = 0;
        for (int b = 0; b < 16; ++b) { s[16 + b] = acc; acc += s[b]; }
    }
}

// one block per bin; ballot-based stable rank — bit-deterministic every call
__global__ __launch_bounds__(256) void sort_scatter_det(
    const int* __restrict__ lengths, int* __restrict__ s)
{
    __shared__ int wsum[4];
    __shared__ int running;
    const int b   = blockIdx.x;
    const int tid = threadIdx.x;
    if (tid == 0) running = s[16 + b];
    __syncthreads();
    for (int c0 = 0; c0 < NTOK; c0 += 256) {
        const int i = c0 + tid;
        const bool f = (lengths[i] - 1 == b);
        const unsigned long long m = __ballot(f);
        const int wv = tid >> 6;
        if ((tid & 63) == 0) wsum[wv] = __popcll(m);
        __syncthreads();
        int excl = 0;
#pragma unroll
        for (int k = 0; k < 4; ++k) if (k < wv) excl += wsum[k];
        const int lanerank = __popcll(m & ((1ull << (tid & 63)) - 1ull));
        if (f) s[48 + running + excl + lanerank] = i;
        const int tot = wsum[0] + wsum[1] + wsum[2] + wsum[3];
        __syncthreads();
        if (tid == 0) running += tot;
        __syncthreads();
    }
}

// ---------------------------------------------------------------------------
// Kernel 0: pack Wg(384x256)+Wp(128x256) fp32 -> bf16 B-fragment layout.
// lane l holds B[k=(l>>4)*8+e][n=l&15], e=0..7. n = c*128 + w*16 + (l&15).
// index: ((w*4+c)*8+kf)*64 + lane, entry = uint4 (8 bf16 along k).
// ---------------------------------------------------------------------------
__global__ __launch_bounds__(256) void pack_weights(
    const float* __restrict__ Wg, const float* __restrict__ Wp,
    uint4* __restrict__ packed)
{
    const int gid  = blockIdx.x * 256 + threadIdx.x;  // 0..16383
    const int lane = gid & 63;
    const int kf   = (gid >> 6) & 7;
    const int c    = (gid >> 9) & 3;
    const int w    = (gid >> 11) & 7;
    const int n    = c * 128 + w * 16 + (lane & 15);
    const int k0   = kf * 32 + (lane >> 4) * 8;
    const float* src = (n < 384) ? (Wg + n * 256 + k0) : (Wp + (n - 384) * 256 + k0);
    uint4 o;
    o.x = f2bf(src[0]) | ((unsigned)f2bf(src[1]) << 16);
    o.y = f2bf(src[2]) | ((unsigned)f2bf(src[3]) << 16);
    o.z = f2bf(src[4]) | ((unsigned)f2bf(src[5]) << 16);
    o.w = f2bf(src[6]) | ((unsigned)f2bf(src[7]) << 16);
    packed[gid] = o;
}

// ---------------------------------------------------------------------------
// Kernel 1: MFMA gated pyramid scan, weights register-resident.
// 4 sorted tokens/WG, 8 waves. X row r = p*4 + t (static across steps).
//
// Register-budget note (R5/R6 post-mortem): the backend budgets VGPRs to the
// occupancy LDS already allows. At 64.5 KB LDS, 2 WGs/CU fit -> 4 waves/EU
// -> 128-reg cap -> wreg spills to scratch (R6: WRITE_SIZE 128 MB, ~400 GB/s).
// lds_pad pushes LDS past 80 KB -> 1 WG/CU -> 2 waves/EU -> 256-reg budget,
// which fits wreg(128)+acc(64)+working(~40) with no spill.
// ---------------------------------------------------------------------------
__global__ __launch_bounds__(512, 2) void scan_mfma(
    const int*   __restrict__ char_ids,
    const int*   __restrict__ char_lengths,
    const float* __restrict__ char_table,
    const float* __restrict__ bg, const float* __restrict__ bp,
    const uint4* __restrict__ Wpacked,
    const int*   __restrict__ order,
    unsigned short* __restrict__ char_repr)
{
    __shared__ __align__(16) float S[TW * SCC * CD];          // 32 KB fp32 state
    __shared__ __align__(16) unsigned short X[64 * 256];      // 32 KB bf16, swizzled
    __shared__ float lds_pad[5120];                           // 20 KB occupancy control
    __shared__ int toksh[TW];
    __shared__ int Lsh[TW];

    const int tid  = threadIdx.x;
    const int lane = tid & 63;
    const int w    = tid >> 6;         // wave 0..7
    const int col  = lane & 15;
    const int q    = lane >> 4;        // 0..3

    if (tid < TW) {
        const int tok = order[blockIdx.x * TW + tid];
        toksh[tid] = tok;
        Lsh[tid]   = char_lengths[tok];
    }

    // ---- weights into registers: wave w's slice, 128 VGPRs, static idx ----
    short8 wreg[4][8];
#pragma unroll
    for (int c = 0; c < 4; ++c)
#pragma unroll
        for (int kf = 0; kf < 8; ++kf) {
            union { uint4 u; short8 s; } cv;
            cv.u = Wpacked[((w * 4 + c) * 8 + kf) * 64 + lane];
            wreg[c][kf] = cv.s;
        }

    const int dj = w * 16 + col;
    float biasv[4];
    biasv[0] = bg[dj];
    biasv[1] = bg[128 + dj];
    biasv[2] = bg[256 + dj];
    biasv[3] = bp[dj];

    __syncthreads();

    // init state: S[t][c][d] = char_table[ids[tok[t]][c]][d]
    for (int i = tid; i < TW * SCC * (CD / 4); i += 512) {
        const int t   = i >> 9;
        const int rem = i & 511;
        const int c   = rem >> 5;
        const int d4  = rem & 31;
        const int id  = char_ids[toksh[t] * SCC + c];
        reinterpret_cast<float4*>(S)[i] =
            reinterpret_cast<const float4*>(char_table + id * CD)[d4];
    }

    int L[TW];
#pragma unroll
    for (int t = 0; t < TW; ++t) L[t] = Lsh[t];
    const int maxL = max(max(L[0], L[1]), max(L[2], L[3]));

    // keep lds_pad alive: maxL >= 1 always, so this never executes, but the
    // compiler can't prove it (maxL comes from global memory).
    if (maxL < 0) { lds_pad[tid] = (float)maxL; S[0] = lds_pad[511 - tid]; }

    __syncthreads();

    // init X once: row r=p*4+t = [S[t][p] | S[t][p+1]] bf16 (contiguous 256f),
    // rows with p=15 zero-filled (never valid, keeps MFMA inputs finite).
    for (int i = tid; i < 64 * 128; i += 512) {
        const int r  = i >> 7;
        const int ku = i & 127;
        const int p  = r >> 2;
        const int t  = r & 3;
        unsigned u = 0u;
        if (p < 15) {
            const float2 v = reinterpret_cast<const float2*>(S + t * 2048 + p * 128)[ku];
            u = f2bf(v.x) | ((unsigned)f2bf(v.y) << 16);
        }
        int baddr = (r << 9) + (ku << 2);
        baddr ^= (r & 7) << 4;
        *reinterpret_cast<unsigned*>(reinterpret_cast<char*>(X) + baddr) = u;
    }
    __syncthreads();

    for (int len = 1; len < maxL; ++len) {
        const int Amax   = maxL - len;
        const int mfrags = (4 * Amax + 15) >> 4;

        f32x4 acc[4][4];   // [m-frag][chunk]
#pragma unroll
        for (int m = 0; m < 4; ++m)
#pragma unroll
            for (int c = 0; c < 4; ++c) acc[m][c] = (f32x4){0.f, 0.f, 0.f, 0.f};

        // ---- MFMA phase: A from LDS X, B from registers ----
#pragma unroll
        for (int kf = 0; kf < 8; ++kf) {
#pragma unroll
            for (int m = 0; m < 4; ++m) {
                if (m < mfrags) {
                    const int row = m * 16 + col;
                    int baddr = (row << 9) + (kf << 6) + (q << 4);
                    baddr ^= (row & 7) << 4;
                    const short8 a = *reinterpret_cast<const short8*>(
                        reinterpret_cast<const char*>(X) + baddr);
#pragma unroll
                    for (int c = 0; c < 4; ++c)
                        acc[m][c] = __builtin_amdgcn_mfma_f32_16x16x32_bf16(
                            a, wreg[c][kf], acc[m][c], 0, 0, 0);
                }
            }
        }

        // ---- combine: lane-local softmax + convex mix. t = i, p = m*4+q ----
#pragma unroll
        for (int m = 0; m < 4; ++m) {
            if (m < mfrags) {
                const int p = m * 4 + q;
#pragma unroll
                for (int i = 0; i < 4; ++i) {
                    const float g0 = acc[m][0][i] + biasv[0];
                    const float g1 = acc[m][1][i] + biasv[1];
                    const float g2 = acc[m][2][i] + biasv[2];
                    const float z  = acc[m][3][i] + biasv[3];
                    const float mx = fmaxf(fmaxf(g0, g1), g2);
                    const float e0 = __expf(g0 - mx);
                    const float e1 = __expf(g1 - mx);
                    const float e2 = __expf(g2 - mx);
                    const float left  = S[i * 2048 + p * 128 + dj];
                    const float right = S[i * 2048 + (p + 1) * 128 + dj];
                    acc[m][0][i] = (e0 * left + e1 * right + e2 * z) / (e0 + e1 + e2);
                }
            }
        }
        __syncthreads();   // all X-reads (MFMA) and S-reads (combine) done

        // ---- write phase: masked fp32 S + bf16 X (left @ p, right @ p-1) ----
#pragma unroll
        for (int m = 0; m < 4; ++m) {
            if (m < mfrags) {
                const int p = m * 4 + q;
#pragma unroll
                for (int i = 0; i < 4; ++i) {
                    const float val = acc[m][0][i];
                    if (p < L[i] - len) S[i * 2048 + p * 128 + dj] = val;
                    const unsigned short bv = f2bf(val);
                    const int rl = m * 16 + q * 4 + i;          // row p*4+i
                    int bl = (rl << 9) + (dj << 1);
                    bl ^= (rl & 7) << 4;
                    *reinterpret_cast<unsigned short*>(
                        reinterpret_cast<char*>(X) + bl) = bv;
                    if (p >= 1) {
                        const int rr = rl - 4;                  // row (p-1)*4+i
                        int br = (rr << 9) + 256 + (dj << 1);
                        br ^= (rr & 7) << 4;
                        *reinterpret_cast<unsigned short*>(
                            reinterpret_cast<char*>(X) + br) = bv;
                    }
                }
            }
        }
        __syncthreads();
    }

    // char representation = S[t][0][:], stored bf16
    for (int i = tid; i < TW * CD; i += 512) {
        const int t = i >> 7, d = i & 127;
        char_repr[toksh[t] * CD + d] = f2bf(S[t * 2048 + d]);
    }
}

// ---------------------------------------------------------------------------
// Kernel 2: out[t][j] = b_out[j] + emb[t] . W_out[j]
// ---------------------------------------------------------------------------
#define TPB2 16

__global__ __launch_bounds__(256) void out_gemm(
    const int*   __restrict__ word_inputs,
    const float* __restrict__ word_table,
    const unsigned short* __restrict__ char_repr,   // bf16 bits
    const float* __restrict__ W_out,
    const float* __restrict__ b_out,
    float*       __restrict__ out)
{
    __shared__ __align__(16) float E[TPB2 * ED];  // 40 KB

    const int tg  = blockIdx.x * TPB2;
    const int tid = threadIdx.x;

    for (int i = tid; i < TPB2 * WD; i += 256) {
        const int tl = i >> 9, k = i & 511;
        E[tl * ED + k] = word_table[(size_t)word_inputs[tg + tl] * WD + k];
    }
    for (int i = tid; i < TPB2 * CD; i += 256) {
        const int tl = i >> 7, k = i & 127;
        union { unsigned u; float f; } qq;
        qq.u = ((unsigned)char_repr[(tg + tl) * CD + k]) << 16;
        E[tl * ED + WD + k] = qq.f;
    }
    __syncthreads();

    const int j0 = tid * 4;
    float acc[TPB2][4];
#pragma unroll
    for (int tl = 0; tl < TPB2; ++tl)
#pragma unroll
        for (int jj = 0; jj < 4; ++jj) acc[tl][jj] = 0.f;

#pragma unroll 2
    for (int kc = 0; kc < ED / 4; ++kc) {
        const int k = kc * 4;
        float4 wr[4];
#pragma unroll
        for (int jj = 0; jj < 4; ++jj)
            wr[jj] = *reinterpret_cast<const float4*>(W_out + (size_t)(j0 + jj) * ED + k);
#pragma unroll
        for (int tl = 0; tl < TPB2; ++tl) {
            const float4 e = *reinterpret_cast<const float4*>(E + tl * ED + k);
#pragma unroll
            for (int jj = 0; jj < 4; ++jj) {
                acc[tl][jj] = fmaf(wr[jj].x, e.x, acc[tl][jj]);
                acc[tl][jj] = fmaf(wr[jj].y, e.y, acc[tl][jj]);
                acc[tl][jj] = fmaf(wr[jj].z, e.z, acc[tl][jj]);
                acc[tl][jj] = fmaf(wr[jj].w, e.w, acc[tl][jj]);
            }
        }
    }

    const float4 bb = *reinterpret_cast<const float4*>(b_out + j0);
#pragma unroll
    for (int tl = 0; tl < TPB2; ++tl) {
        float4 r;
        r.x = acc[tl][0] + bb.x;
        r.y = acc[tl][1] + bb.y;
        r.z = acc[tl][2] + bb.z;
        r.w = acc[tl][3] + bb.w;
        *reinterpret_cast<float4*>(out + (size_t)(tg + tl) * OD + j0) = r;
    }
}

// ---------------------------------------------------------------------------

extern "C" void kernel_launch(void* const* d_in, const int* in_sizes, int n_in,
                              void* d_out, int out_size, void* d_ws, size_t ws_size,
                              hipStream_t stream)
{
    const int*   word_inputs  = (const int*)  d_in[0];
    const int*   char_ids     = (const int*)  d_in[1];
    const int*   char_lengths = (const int*)  d_in[2];
    const float* word_table   = (const float*)d_in[3];
    const float* char_table   = (const float*)d_in[4];
    const float* Wg           = (const float*)d_in[5];
    const float* bg           = (const float*)d_in[6];
    const float* Wp           = (const float*)d_in[7];
    const float* bp           = (const float*)d_in[8];
    const float* W_out        = (const float*)d_in[9];
    const float* b_out        = (const float*)d_in[10];

    float* out = (float*)d_out;
    unsigned short* char_repr = (unsigned short*)d_ws;              // 2 MB bf16
    uint4* Wpacked = (uint4*)((char*)d_ws + 2 * 1024 * 1024);       // 256 KB
    int*   sortbuf = (int*)((char*)d_ws + 2 * 1024 * 1024 + 256 * 1024);
    const int* order = sortbuf + 48;

    pack_weights<<<64, 256, 0, stream>>>(Wg, Wp, Wpacked);
    sort_zero<<<1, 64, 0, stream>>>(sortbuf);
    sort_hist<<<NTOK / 256, 256, 0, stream>>>(char_lengths, sortbuf);
    sort_prefix<<<1, 64, 0, stream>>>(sortbuf);
    sort_scatter_det<<<16, 256, 0, stream>>>(char_lengths, sortbuf);

    scan_mfma<<<NTOK / TW, 512, 0, stream>>>(char_ids, char_lengths, char_table,
                                             bg, bp, Wpacked, order, char_repr);
    out_gemm<<<NTOK / TPB2, 256, 0, stream>>>(word_inputs, word_table, char_repr,
                                              W_out, b_out, out);
}